// Round 5
// 616.766 us; speedup vs baseline: 1.0263x; 1.0263x over previous
//
#include <hip/hip_runtime.h>
#include <math.h>

constexpr int S = 200;
constexpr int SS = S * S;           // 40000
constexpr int SLICE = 640000;       // 200*3200 complex
constexpr int MP = 224;             // padded rows (7 tiles of 32)
constexpr int KP = 224;             // padded K (7 chunks of 32)
constexpr int PS = MP * KP;         // 50176 elements per A bf16 plane

typedef short short8 __attribute__((ext_vector_type(8)));
typedef short short4v __attribute__((ext_vector_type(4)));
typedef float float4v __attribute__((ext_vector_type(4)));

// ---------------- threefry2x32 (JAX-compatible, 20 rounds) ----------------
struct TFOut { unsigned a, b; };

__host__ __device__ constexpr TFOut tf2x32(unsigned k0, unsigned k1,
                                           unsigned x0, unsigned x1) {
  unsigned ks2 = k0 ^ k1 ^ 0x1BD11BDAu;
  unsigned ks[3] = {k0, k1, ks2};
  const int R0[4] = {13, 15, 26, 6};
  const int R1[4] = {17, 29, 16, 24};
  x0 += ks[0]; x1 += ks[1];
  for (int i = 0; i < 5; ++i) {
    const int* R = (i & 1) ? R1 : R0;
    for (int j = 0; j < 4; ++j) {
      x0 += x1;
      x1 = (x1 << R[j]) | (x1 >> (32 - R[j]));
      x1 ^= x0;
    }
    x0 += ks[(i + 1) % 3];
    x1 += ks[(i + 2) % 3] + (unsigned)(i + 1);
  }
  return {x0, x1};
}

constexpr TFOut KEY1 = tf2x32(0u, 42u, 0u, 0u);
constexpr TFOut KEY2 = tf2x32(0u, 42u, 0u, 1u);

// ---------------- gumbel helpers ----------------
__device__ inline float bits_to_u(unsigned bits) {
  float f = __uint_as_float((bits >> 9) | 0x3f800000u) - 1.0f;
  f = f + 1e-10f;
  return fmaxf(1e-10f, f);
}
__device__ inline float u_to_g_exact(float u) {
  float l1 = (float)log((double)u);
  float l2 = (float)log((double)(-l1));
  return -l2;
}
__device__ inline float u_to_g_fast(float u) {
  float l1 = logf(u);
  float l2 = logf(-l1);
  return -l2;
}
__device__ inline unsigned ordf(float f) {
  unsigned u = __float_as_uint(f);
  return (u & 0x80000000u) ? ~u : (u | 0x80000000u);
}
__device__ inline float unordf(unsigned u) {
  return (u & 0x80000000u) ? __uint_as_float(u ^ 0x80000000u)
                           : __uint_as_float(~u);
}
__device__ inline unsigned long long packcand(float val, int p) {
  return ((unsigned long long)ordf(val) << 32) | (unsigned)(255 - p);
}
__device__ inline unsigned long long umax64(unsigned long long a,
                                            unsigned long long b) {
  return a > b ? a : b;
}
__device__ inline unsigned long long wave_max_ull(unsigned long long v) {
#pragma unroll
  for (int s = 32; s > 0; s >>= 1)
    v = umax64(v, (unsigned long long)__shfl_xor((unsigned long long)v, s, 64));
  return v;
}
__device__ inline unsigned wave_max_u32(unsigned v) {
#pragma unroll
  for (int s = 32; s > 0; s >>= 1) {
    unsigned o = (unsigned)__shfl_xor((int)v, s, 64);
    v = v > o ? v : o;
  }
  return v;
}

// One wave per pixel: lanes hold p = lane + 64*jj, jj=0..3. Identical RNG
// bitstream (idx = q*256+p). 32-bit packed (value-top24 | 255-p) wave-local
// argmax, no LDS, no __syncthreads. Truncation to 24 value bits only widens
// the flagged set of the existing eps-recheck (safe); near-ties resolved by
// the exact double-log path, same as before.
__global__ __launch_bounds__(256) void gumbel_kernel(
    const float* __restrict__ voltage, const float* __restrict__ phase_func,
    const float* __restrict__ intensity_func, float2* __restrict__ PT) {
  const int tid = threadIdx.x;
  const int wv = tid >> 6, lane = tid & 63;
  const int q = blockIdx.x * 4 + wv;

  float v4[4], c1[4], c2[4], u1s[4], u2s[4];
  unsigned pk1 = 0u, pk2 = 0u;
#pragma unroll
  for (int jj = 0; jj < 4; ++jj) {
    const int p = lane + 64 * jj;
    const unsigned idx = (unsigned)q * 256u + (unsigned)p;
    v4[jj] = voltage[(size_t)q * 256 + p];
    TFOut r1 = tf2x32(KEY1.a, KEY1.b, 0u, idx);
    TFOut r2 = tf2x32(KEY2.a, KEY2.b, 0u, idx);
    u1s[jj] = bits_to_u(r1.a ^ r1.b);
    u2s[jj] = bits_to_u(r2.a ^ r2.b);
    c1[jj] = (v4[jj] + u_to_g_fast(u1s[jj])) * 0.1f;
    c2[jj] = (v4[jj] + u_to_g_fast(u2s[jj])) * 0.1f;
    unsigned t1 = (ordf(c1[jj]) & 0xFFFFFF00u) | (unsigned)(255 - p);
    unsigned t2 = (ordf(c2[jj]) & 0xFFFFFF00u) | (unsigned)(255 - p);
    pk1 = pk1 > t1 ? pk1 : t1;
    pk2 = pk2 > t2 ? pk2 : t2;
  }
  pk1 = wave_max_u32(pk1);
  pk2 = wave_max_u32(pk2);

  const float eps = 1e-5f;
  const float thr1 = unordf(pk1 & 0xFFFFFF00u) - eps;
  const float thr2 = unordf(pk2 & 0xFFFFFF00u) - eps;
  bool f1[4], f2[4];
  int n1 = 0, n2 = 0;
#pragma unroll
  for (int jj = 0; jj < 4; ++jj) {
    f1[jj] = c1[jj] >= thr1;
    f2[jj] = c2[jj] >= thr2;
    n1 += __popcll(__ballot(f1[jj]));
    n2 += __popcll(__ballot(f2[jj]));
  }

  unsigned i1, i2;
  if (n1 > 1 || n2 > 1) {  // rare wave-uniform exact path
    unsigned long long e1 = 0ull, e2 = 0ull;
#pragma unroll
    for (int jj = 0; jj < 4; ++jj) {
      const int p = lane + 64 * jj;
      if (f1[jj]) e1 = umax64(e1, packcand((v4[jj] + u_to_g_exact(u1s[jj])) / 10.0f, p));
      if (f2[jj]) e2 = umax64(e2, packcand((v4[jj] + u_to_g_exact(u2s[jj])) / 10.0f, p));
    }
    e1 = wave_max_ull(e1);
    e2 = wave_max_ull(e2);
    i1 = 255u - (unsigned)(e1 & 0xFFu);
    i2 = 255u - (unsigned)(e2 & 0xFFu);
  } else {
    i1 = 255u - (pk1 & 0xFFu);
    i2 = 255u - (pk2 & 0xFFu);
  }
  if (lane == 0) {
    float phi = phase_func[i1];
    float amp = intensity_func[i2] * 6.0f;
    PT[q] = make_float2(amp * cosf(phi), amp * sinf(phi));
  }
}

// ---------------- tables ----------------
__device__ inline unsigned short bf16_rne(float x) {
  unsigned u = __float_as_uint(x);
  return (unsigned short)((u + 0x7FFFu + ((u >> 16) & 1u)) >> 16);
}
__device__ inline void split_bf16(float x, unsigned short& h, unsigned short& l) {
  h = bf16_rne(x);
  float hf = __uint_as_float(((unsigned)h) << 16);
  l = bf16_rne(x - hf);
}

// bf16 hi/lo planes of F and G (padded 224x224) + transposed h table.
// Twiddles built per-block in LDS (fused, no separate launch).
__global__ __launch_bounds__(256) void build_planes_ht(
    const float* __restrict__ h_real, const float* __restrict__ h_imag,
    unsigned short* __restrict__ PL, float2* __restrict__ HT) {
  __shared__ float2 tw[S];
  const int t = threadIdx.x;
  if (t < S) {
    double ang = -2.0 * 3.1415926535897932384626433832795 * (double)t / (double)S;
    tw[t] = make_float2((float)cos(ang), (float)sin(ang));
  }
  __syncthreads();
  int idx = blockIdx.x * 256 + t;  // 196*256 = 50176 = PS exact
  int m = idx / KP, k = idx - (idx / KP) * KP;
  float fr = 0.f, fi = 0.f;
  if (m < S && k < S) {
    float2 tv = tw[(m * k) % S];
    fr = tv.x; fi = tv.y;
  }
  unsigned short h, l;
  split_bf16(fr, h, l);           PL[0 * PS + idx] = h; PL[1 * PS + idx] = l;
  split_bf16(fi, h, l);           PL[2 * PS + idx] = h; PL[3 * PS + idx] = l;
  split_bf16(fr * 0.005f, h, l);  PL[4 * PS + idx] = h; PL[5 * PS + idx] = l;
  split_bf16(-fi * 0.005f, h, l); PL[6 * PS + idx] = h; PL[7 * PS + idx] = l;
  if (idx < SS) {  // HT[n][k] = h[k][n]
    int kk = idx / S, n = idx - (idx / S) * S;
    HT[n * S + kk] = make_float2(h_real[idx], h_imag[idx]);
  }
}

// ---------------- MFMA split-bf16 GEMM, 32x32 tiles ----------------
// out[m][(b,n)] = sum_k Op[m][k] * Bop[k][(b,n)], Op = F or G (A planes).
// MODE 0: Bop = waves[b][k][n] (re/im planes)
// MODE 1: Bop = Sprev[b*200+n][k]
// MODE 2: Bop = Sprev[b*200+n][k] * h[k][n]  (via HT[n][k])
// Output stored Sout[(b*200+m)*200 + n]. FINAL: multiply by PT[n*200+m].
template <int MODE, bool FINAL>
__global__ __launch_bounds__(256) void gemm_mfma(
    const unsigned short* __restrict__ APL, const float* __restrict__ Wre,
    const float* __restrict__ Wim, const float2* __restrict__ Sprev,
    const float2* __restrict__ HT, const float2* __restrict__ PT,
    float2* __restrict__ Sout) {
  __shared__ short As[4][32][40];  // planes rh,rl,ih,il ; [m][k] k-contig
  __shared__ short Bs[4][32][40];  // planes ; [n][k] k-contig
  const int tid = threadIdx.x;
  const int wave = tid >> 6, lane = tid & 63, quad = lane >> 4, l15 = lane & 15;
  const int mb = blockIdx.x * 32;  // 0..192 (padded M=224)
  const int cb = blockIdx.y * 32;  // flat col base, N=3200
  const int mh = wave & 1, nh = wave >> 1;

  // A staging: plane, row, two k-groups {g*8, g*8+16}
  const int ap_ = tid >> 6;
  const int ar = (tid & 63) >> 1;
  const int ag = (tid & 1) * 8;
  const unsigned short* abase = APL + ap_ * PS + (mb + ar) * KP;

  // B staging: col (0..31), k-quad (0,4,..,28)
  const int bc = tid >> 3;
  const int bkq = (tid & 7) * 4;
  const int cB = cb + bc;
  const int bB0 = cB / S;
  const int nB0 = cB - bB0 * S;

  float4v accRR = {0.f, 0.f, 0.f, 0.f}, accII = {0.f, 0.f, 0.f, 0.f};
  float4v accRI = {0.f, 0.f, 0.f, 0.f}, accIR = {0.f, 0.f, 0.f, 0.f};

  for (int ch = 0; ch < 7; ++ch) {
    const int kc = ch * 32;
    short8 a0 = *(const short8*)(abase + kc + ag);
    short8 a1 = *(const short8*)(abase + kc + ag + 16);

    float re[4], im[4];
#pragma unroll
    for (int j = 0; j < 4; ++j) { re[j] = 0.f; im[j] = 0.f; }
    const int gk = kc + bkq;
    if (gk < S) {  // group of 4 entirely valid (S%4==0)
      if (MODE == 0) {
#pragma unroll
        for (int j = 0; j < 4; ++j) {
          re[j] = Wre[(long)bB0 * SS + (gk + j) * S + nB0];
          im[j] = Wim[(long)bB0 * SS + (gk + j) * S + nB0];
        }
      } else {
        const float2* bp = &Sprev[(long)(bB0 * S + nB0) * S + gk];
#pragma unroll
        for (int j = 0; j < 4; ++j) { re[j] = bp[j].x; im[j] = bp[j].y; }
        if (MODE == 2) {
          const float2* hp = &HT[(long)nB0 * S + gk];
#pragma unroll
          for (int j = 0; j < 4; ++j) {
            float2 hv = hp[j];
            float tr = re[j] * hv.x - im[j] * hv.y;
            im[j] = re[j] * hv.y + im[j] * hv.x;
            re[j] = tr;
          }
        }
      }
    }
    short4v rh, rl, ih, il;
#pragma unroll
    for (int j = 0; j < 4; ++j) {
      unsigned short h_, l_;
      split_bf16(re[j], h_, l_); rh[j] = (short)h_; rl[j] = (short)l_;
      split_bf16(im[j], h_, l_); ih[j] = (short)h_; il[j] = (short)l_;
    }

    __syncthreads();  // previous chunk's frag reads complete
    *(short8*)&As[ap_][ar][ag] = a0;
    *(short8*)&As[ap_][ar][ag + 16] = a1;
    *(short4v*)&Bs[0][bc][bkq] = rh;
    *(short4v*)&Bs[1][bc][bkq] = rl;
    *(short4v*)&Bs[2][bc][bkq] = ih;
    *(short4v*)&Bs[3][bc][bkq] = il;
    __syncthreads();

    const int amr = mh * 16 + l15;
    const int bnr = nh * 16 + l15;
    short8 Arh = *(const short8*)&As[0][amr][quad * 8];
    short8 Arl = *(const short8*)&As[1][amr][quad * 8];
    short8 Aih = *(const short8*)&As[2][amr][quad * 8];
    short8 Ail = *(const short8*)&As[3][amr][quad * 8];
    short8 Brh = *(const short8*)&Bs[0][bnr][quad * 8];
    short8 Brl = *(const short8*)&Bs[1][bnr][quad * 8];
    short8 Bih = *(const short8*)&Bs[2][bnr][quad * 8];
    short8 Bil = *(const short8*)&Bs[3][bnr][quad * 8];

    accRR = __builtin_amdgcn_mfma_f32_16x16x32_bf16(Arh, Brh, accRR, 0, 0, 0);
    accRR = __builtin_amdgcn_mfma_f32_16x16x32_bf16(Arh, Brl, accRR, 0, 0, 0);
    accRR = __builtin_amdgcn_mfma_f32_16x16x32_bf16(Arl, Brh, accRR, 0, 0, 0);
    accII = __builtin_amdgcn_mfma_f32_16x16x32_bf16(Aih, Bih, accII, 0, 0, 0);
    accII = __builtin_amdgcn_mfma_f32_16x16x32_bf16(Aih, Bil, accII, 0, 0, 0);
    accII = __builtin_amdgcn_mfma_f32_16x16x32_bf16(Ail, Bih, accII, 0, 0, 0);
    accRI = __builtin_amdgcn_mfma_f32_16x16x32_bf16(Arh, Bih, accRI, 0, 0, 0);
    accRI = __builtin_amdgcn_mfma_f32_16x16x32_bf16(Arh, Bil, accRI, 0, 0, 0);
    accRI = __builtin_amdgcn_mfma_f32_16x16x32_bf16(Arl, Bih, accRI, 0, 0, 0);
    accIR = __builtin_amdgcn_mfma_f32_16x16x32_bf16(Aih, Brh, accIR, 0, 0, 0);
    accIR = __builtin_amdgcn_mfma_f32_16x16x32_bf16(Aih, Brl, accIR, 0, 0, 0);
    accIR = __builtin_amdgcn_mfma_f32_16x16x32_bf16(Ail, Brh, accIR, 0, 0, 0);
  }

  // epilogue: C/D layout col=l15, row=quad*4+r
  const int cg = cb + nh * 16 + l15;
  const int b = cg / S;
  const int n = cg - b * S;
#pragma unroll
  for (int r = 0; r < 4; ++r) {
    const int m = mb + mh * 16 + quad * 4 + r;
    if (m < S) {
      float Cr = accRR[r] - accII[r];
      float Ci = accRI[r] + accIR[r];
      if (FINAL) {
        float2 pt = PT[n * S + m];
        float tr = Cr * pt.x - Ci * pt.y;
        Ci = Cr * pt.y + Ci * pt.x;
        Cr = tr;
      }
      Sout[(long)(b * S + m) * S + n] = make_float2(Cr, Ci);
    }
  }
}

// ---------------- 10x pixel expansion ----------------
// S4[(b*200+j)*200 + i] = X_b[i][j] (phase applied). out (16,2000,2000,2).
__global__ __launch_bounds__(256) void expand_kernel(
    const float2* __restrict__ S4, float4v* __restrict__ out) {
  unsigned q = blockIdx.x * 256u + threadIdx.x;  // < 32,000,000 exact
  unsigned p0 = q * 2u;
  unsigned b = p0 / 4000000u;
  unsigned rem = p0 - b * 4000000u;
  unsigned r = rem / 2000u;
  unsigned c0 = rem - r * 2000u;
  unsigned i = r / 10u;
  unsigned dr = r - i * 10u;
  float4v o = {0.f, 0.f, 0.f, 0.f};
  if (dr - 1u <= 7u) {  // dr in [1,8]
    unsigned j = c0 / 10u;
    unsigned dc = c0 - j * 10u;  // even: 0,2,4,6,8
    float2 xv = S4[(b * 200u + j) * 200u + i];
    if (dc != 0u) { o.x = xv.x; o.y = xv.y; }
    if (dc != 8u) { o.z = xv.x; o.w = xv.y; }
  }
  __builtin_nontemporal_store(o, &out[q]);  // write-once stream, skip L2 alloc
}

// ---------------- launch ----------------
extern "C" void kernel_launch(void* const* d_in, const int* in_sizes, int n_in,
                              void* d_out, int out_size, void* d_ws, size_t ws_size,
                              hipStream_t stream) {
  const float* waves_real = (const float*)d_in[0];
  const float* waves_imag = (const float*)d_in[1];
  const float* h_real = (const float*)d_in[2];
  const float* h_imag = (const float*)d_in[3];
  const float* voltage = (const float*)d_in[4];
  const float* phase_func = (const float*)d_in[5];
  const float* intensity_func = (const float*)d_in[6];

  float2* HT = (float2*)d_ws;      // 40000
  float2* PT = HT + SS;            // 40000
  float2* S1 = PT + SS;            // 640000 each
  float2* S2 = S1 + SLICE;
  float2* S3 = S2 + SLICE;
  float2* S4 = S3 + SLICE;
  unsigned short* PL = (unsigned short*)(S4 + SLICE);  // 8 * 50176 bf16

  build_planes_ht<<<196, 256, 0, stream>>>(h_real, h_imag, PL, HT);
  gumbel_kernel<<<10000, 256, 0, stream>>>(voltage, phase_func, intensity_func, PT);

  const unsigned short* FP = PL;           // F planes
  const unsigned short* GP = PL + 4 * PS;  // G planes
  dim3 g(7, 100);  // 700 blocks: ~2.7 blocks/CU
  // S1[b*200+m][n] = T1_b[m][n],  T1_b = F @ W_b
  gemm_mfma<0, false><<<g, 256, 0, stream>>>(FP, waves_real, waves_imag,
                                             nullptr, nullptr, nullptr, S1);
  // S2[b*200+m][n] = T2_b[n][m],  T2_b = T1_b @ F  (computed as F @ T1_b^T)
  gemm_mfma<1, false><<<g, 256, 0, stream>>>(FP, nullptr, nullptr, S1,
                                             nullptr, nullptr, S2);
  // S3[b*200+m][n] = T4_b[m][n],  T4_b = G @ (T2_b .* h)
  gemm_mfma<2, false><<<g, 256, 0, stream>>>(GP, nullptr, nullptr, S2,
                                             HT, nullptr, S3);
  // S4[b*200+m][n] = X_b[n][m]*PT, X_b = T4_b @ G  (computed as G @ T4_b^T)
  gemm_mfma<1, true><<<g, 256, 0, stream>>>(GP, nullptr, nullptr, S3,
                                            nullptr, PT, S4);

  expand_kernel<<<125000, 256, 0, stream>>>(S4, (float4v*)d_out);
}

// Round 9
// 615.725 us; speedup vs baseline: 1.0280x; 1.0017x over previous
//
#include <hip/hip_runtime.h>
#include <math.h>

constexpr int S = 200;
constexpr int SS = S * S;           // 40000
constexpr int SLICE = 640000;       // 200*3200 complex
constexpr int MP = 224;             // padded rows (7 tiles of 32)
constexpr int KP = 224;             // padded K (7 chunks of 32)
constexpr int PS = MP * KP;         // 50176 elements per A bf16 plane

typedef short short8 __attribute__((ext_vector_type(8)));
typedef short short4v __attribute__((ext_vector_type(4)));
typedef float float4v __attribute__((ext_vector_type(4)));

// ---------------- threefry2x32 (JAX-compatible, 20 rounds) ----------------
struct TFOut { unsigned a, b; };

__host__ __device__ constexpr TFOut tf2x32(unsigned k0, unsigned k1,
                                           unsigned x0, unsigned x1) {
  unsigned ks2 = k0 ^ k1 ^ 0x1BD11BDAu;
  unsigned ks[3] = {k0, k1, ks2};
  const int R0[4] = {13, 15, 26, 6};
  const int R1[4] = {17, 29, 16, 24};
  x0 += ks[0]; x1 += ks[1];
  for (int i = 0; i < 5; ++i) {
    const int* R = (i & 1) ? R1 : R0;
    for (int j = 0; j < 4; ++j) {
      x0 += x1;
      x1 = (x1 << R[j]) | (x1 >> (32 - R[j]));
      x1 ^= x0;
    }
    x0 += ks[(i + 1) % 3];
    x1 += ks[(i + 2) % 3] + (unsigned)(i + 1);
  }
  return {x0, x1};
}

constexpr TFOut KEY1 = tf2x32(0u, 42u, 0u, 0u);
constexpr TFOut KEY2 = tf2x32(0u, 42u, 0u, 1u);

// ---------------- gumbel helpers ----------------
__device__ inline float bits_to_u(unsigned bits) {
  float f = __uint_as_float((bits >> 9) | 0x3f800000u) - 1.0f;
  f = f + 1e-10f;
  return fmaxf(1e-10f, f);
}
__device__ inline float u_to_g_exact(float u) {
  float l1 = (float)log((double)u);
  float l2 = (float)log((double)(-l1));
  return -l2;
}
__device__ inline float u_to_g_fast(float u) {
  float l1 = logf(u);
  float l2 = logf(-l1);
  return -l2;
}
__device__ inline unsigned ordf(float f) {
  unsigned u = __float_as_uint(f);
  return (u & 0x80000000u) ? ~u : (u | 0x80000000u);
}
__device__ inline float unordf(unsigned u) {
  return (u & 0x80000000u) ? __uint_as_float(u ^ 0x80000000u)
                           : __uint_as_float(~u);
}
__device__ inline unsigned long long packcand(float val, int p) {
  return ((unsigned long long)ordf(val) << 32) | (unsigned)(255 - p);
}
__device__ inline unsigned long long umax64(unsigned long long a,
                                            unsigned long long b) {
  return a > b ? a : b;
}
__device__ inline unsigned long long wave_max_ull(unsigned long long v) {
#pragma unroll
  for (int s = 32; s > 0; s >>= 1)
    v = umax64(v, (unsigned long long)__shfl_xor((unsigned long long)v, s, 64));
  return v;
}
__device__ inline unsigned wave_max_u32(unsigned v) {
#pragma unroll
  for (int s = 32; s > 0; s >>= 1) {
    unsigned o = (unsigned)__shfl_xor((int)v, s, 64);
    v = v > o ? v : o;
  }
  return v;
}

// One wave per pixel (PASSED round 5): lanes hold p = lane + 64*jj. Identical
// RNG bitstream; 24-bit truncated fast argmax only widens the eps-recheck set;
// near-ties resolved by the exact double-log path. No LDS, no barriers.
__global__ __launch_bounds__(256) void gumbel_kernel(
    const float* __restrict__ voltage, const float* __restrict__ phase_func,
    const float* __restrict__ intensity_func, float2* __restrict__ PT) {
  const int tid = threadIdx.x;
  const int wv = tid >> 6, lane = tid & 63;
  const int q = blockIdx.x * 4 + wv;

  float v4[4], c1[4], c2[4], u1s[4], u2s[4];
  unsigned pk1 = 0u, pk2 = 0u;
#pragma unroll
  for (int jj = 0; jj < 4; ++jj) {
    const int p = lane + 64 * jj;
    const unsigned idx = (unsigned)q * 256u + (unsigned)p;
    v4[jj] = voltage[(size_t)q * 256 + p];
    TFOut r1 = tf2x32(KEY1.a, KEY1.b, 0u, idx);
    TFOut r2 = tf2x32(KEY2.a, KEY2.b, 0u, idx);
    u1s[jj] = bits_to_u(r1.a ^ r1.b);
    u2s[jj] = bits_to_u(r2.a ^ r2.b);
    c1[jj] = (v4[jj] + u_to_g_fast(u1s[jj])) * 0.1f;
    c2[jj] = (v4[jj] + u_to_g_fast(u2s[jj])) * 0.1f;
    unsigned t1 = (ordf(c1[jj]) & 0xFFFFFF00u) | (unsigned)(255 - p);
    unsigned t2 = (ordf(c2[jj]) & 0xFFFFFF00u) | (unsigned)(255 - p);
    pk1 = pk1 > t1 ? pk1 : t1;
    pk2 = pk2 > t2 ? pk2 : t2;
  }
  pk1 = wave_max_u32(pk1);
  pk2 = wave_max_u32(pk2);

  const float eps = 1e-5f;
  const float thr1 = unordf(pk1 & 0xFFFFFF00u) - eps;
  const float thr2 = unordf(pk2 & 0xFFFFFF00u) - eps;
  bool f1[4], f2[4];
  int n1 = 0, n2 = 0;
#pragma unroll
  for (int jj = 0; jj < 4; ++jj) {
    f1[jj] = c1[jj] >= thr1;
    f2[jj] = c2[jj] >= thr2;
    n1 += __popcll(__ballot(f1[jj]));
    n2 += __popcll(__ballot(f2[jj]));
  }

  unsigned i1, i2;
  if (n1 > 1 || n2 > 1) {  // rare wave-uniform exact path
    unsigned long long e1 = 0ull, e2 = 0ull;
#pragma unroll
    for (int jj = 0; jj < 4; ++jj) {
      const int p = lane + 64 * jj;
      if (f1[jj]) e1 = umax64(e1, packcand((v4[jj] + u_to_g_exact(u1s[jj])) / 10.0f, p));
      if (f2[jj]) e2 = umax64(e2, packcand((v4[jj] + u_to_g_exact(u2s[jj])) / 10.0f, p));
    }
    e1 = wave_max_ull(e1);
    e2 = wave_max_ull(e2);
    i1 = 255u - (unsigned)(e1 & 0xFFu);
    i2 = 255u - (unsigned)(e2 & 0xFFu);
  } else {
    i1 = 255u - (pk1 & 0xFFu);
    i2 = 255u - (pk2 & 0xFFu);
  }
  if (lane == 0) {
    float phi = phase_func[i1];
    float amp = intensity_func[i2] * 6.0f;
    PT[q] = make_float2(amp * cosf(phi), amp * sinf(phi));
  }
}

// ---------------- tables ----------------
__device__ inline unsigned short bf16_rne(float x) {
  unsigned u = __float_as_uint(x);
  return (unsigned short)((u + 0x7FFFu + ((u >> 16) & 1u)) >> 16);
}
__device__ inline void split_bf16(float x, unsigned short& h, unsigned short& l) {
  h = bf16_rne(x);
  float hf = __uint_as_float(((unsigned)h) << 16);
  l = bf16_rne(x - hf);
}

// bf16 hi/lo planes of F and G (padded 224x224) + transposed h table.
// Twiddles built per-block in LDS (fused, no separate launch).
__global__ __launch_bounds__(256) void build_planes_ht(
    const float* __restrict__ h_real, const float* __restrict__ h_imag,
    unsigned short* __restrict__ PL, float2* __restrict__ HT) {
  __shared__ float2 tw[S];
  const int t = threadIdx.x;
  if (t < S) {
    double ang = -2.0 * 3.1415926535897932384626433832795 * (double)t / (double)S;
    tw[t] = make_float2((float)cos(ang), (float)sin(ang));
  }
  __syncthreads();
  int idx = blockIdx.x * 256 + t;  // 196*256 = 50176 = PS exact
  int m = idx / KP, k = idx - (idx / KP) * KP;
  float fr = 0.f, fi = 0.f;
  if (m < S && k < S) {
    float2 tv = tw[(m * k) % S];
    fr = tv.x; fi = tv.y;
  }
  unsigned short h, l;
  split_bf16(fr, h, l);           PL[0 * PS + idx] = h; PL[1 * PS + idx] = l;
  split_bf16(fi, h, l);           PL[2 * PS + idx] = h; PL[3 * PS + idx] = l;
  split_bf16(fr * 0.005f, h, l);  PL[4 * PS + idx] = h; PL[5 * PS + idx] = l;
  split_bf16(-fi * 0.005f, h, l); PL[6 * PS + idx] = h; PL[7 * PS + idx] = l;
  if (idx < SS) {  // HT[n][k] = h[k][n]
    int kk = idx / S, n = idx - (idx / S) * S;
    HT[n * S + kk] = make_float2(h_real[idx], h_imag[idx]);
  }
}

// ---------------- MFMA split-bf16 GEMM, 32x32 tiles ----------------
// out[m][(b,n)] = sum_k Op[m][k] * Bop[k][(b,n)], Op = F or G (A planes).
// MODE 0: Bop = waves[b][k][n] (re/im planes)
// MODE 1: Bop = Sprev[b*200+n][k]
// MODE 2: Bop = Sprev[b*200+n][k] * h[k][n]  (via HT[n][k])
// Output stored Sout[(b*200+m)*200 + n]. FINAL: multiply by PT[n*200+m].
template <int MODE, bool FINAL>
__global__ __launch_bounds__(256) void gemm_mfma(
    const unsigned short* __restrict__ APL, const float* __restrict__ Wre,
    const float* __restrict__ Wim, const float2* __restrict__ Sprev,
    const float2* __restrict__ HT, const float2* __restrict__ PT,
    float2* __restrict__ Sout) {
  __shared__ short As[4][32][40];  // planes rh,rl,ih,il ; [m][k] k-contig
  __shared__ short Bs[4][32][40];  // planes ; [n][k] k-contig
  const int tid = threadIdx.x;
  const int wave = tid >> 6, lane = tid & 63, quad = lane >> 4, l15 = lane & 15;
  const int mb = blockIdx.x * 32;  // 0..192 (padded M=224)
  const int cb = blockIdx.y * 32;  // flat col base, N=3200
  const int mh = wave & 1, nh = wave >> 1;

  // A staging: plane, row, two k-groups {g*8, g*8+16}
  const int ap_ = tid >> 6;
  const int ar = (tid & 63) >> 1;
  const int ag = (tid & 1) * 8;
  const unsigned short* abase = APL + ap_ * PS + (mb + ar) * KP;

  // B staging: col (0..31), k-quad (0,4,..,28)
  const int bc = tid >> 3;
  const int bkq = (tid & 7) * 4;
  const int cB = cb + bc;
  const int bB0 = cB / S;
  const int nB0 = cB - bB0 * S;

  float4v accRR = {0.f, 0.f, 0.f, 0.f}, accII = {0.f, 0.f, 0.f, 0.f};
  float4v accRI = {0.f, 0.f, 0.f, 0.f}, accIR = {0.f, 0.f, 0.f, 0.f};

  for (int ch = 0; ch < 7; ++ch) {
    const int kc = ch * 32;
    short8 a0 = *(const short8*)(abase + kc + ag);
    short8 a1 = *(const short8*)(abase + kc + ag + 16);

    float re[4], im[4];
#pragma unroll
    for (int j = 0; j < 4; ++j) { re[j] = 0.f; im[j] = 0.f; }
    const int gk = kc + bkq;
    if (gk < S) {  // group of 4 entirely valid (S%4==0)
      if (MODE == 0) {
#pragma unroll
        for (int j = 0; j < 4; ++j) {
          re[j] = Wre[(long)bB0 * SS + (gk + j) * S + nB0];
          im[j] = Wim[(long)bB0 * SS + (gk + j) * S + nB0];
        }
      } else {
        const float2* bp = &Sprev[(long)(bB0 * S + nB0) * S + gk];
#pragma unroll
        for (int j = 0; j < 4; ++j) { re[j] = bp[j].x; im[j] = bp[j].y; }
        if (MODE == 2) {
          const float2* hp = &HT[(long)nB0 * S + gk];
#pragma unroll
          for (int j = 0; j < 4; ++j) {
            float2 hv = hp[j];
            float tr = re[j] * hv.x - im[j] * hv.y;
            im[j] = re[j] * hv.y + im[j] * hv.x;
            re[j] = tr;
          }
        }
      }
    }
    short4v rh, rl, ih, il;
#pragma unroll
    for (int j = 0; j < 4; ++j) {
      unsigned short h_, l_;
      split_bf16(re[j], h_, l_); rh[j] = (short)h_; rl[j] = (short)l_;
      split_bf16(im[j], h_, l_); ih[j] = (short)h_; il[j] = (short)l_;
    }

    __syncthreads();  // previous chunk's frag reads complete
    *(short8*)&As[ap_][ar][ag] = a0;
    *(short8*)&As[ap_][ar][ag + 16] = a1;
    *(short4v*)&Bs[0][bc][bkq] = rh;
    *(short4v*)&Bs[1][bc][bkq] = rl;
    *(short4v*)&Bs[2][bc][bkq] = ih;
    *(short4v*)&Bs[3][bc][bkq] = il;
    __syncthreads();

    const int amr = mh * 16 + l15;
    const int bnr = nh * 16 + l15;
    short8 Arh = *(const short8*)&As[0][amr][quad * 8];
    short8 Arl = *(const short8*)&As[1][amr][quad * 8];
    short8 Aih = *(const short8*)&As[2][amr][quad * 8];
    short8 Ail = *(const short8*)&As[3][amr][quad * 8];
    short8 Brh = *(const short8*)&Bs[0][bnr][quad * 8];
    short8 Brl = *(const short8*)&Bs[1][bnr][quad * 8];
    short8 Bih = *(const short8*)&Bs[2][bnr][quad * 8];
    short8 Bil = *(const short8*)&Bs[3][bnr][quad * 8];

    accRR = __builtin_amdgcn_mfma_f32_16x16x32_bf16(Arh, Brh, accRR, 0, 0, 0);
    accRR = __builtin_amdgcn_mfma_f32_16x16x32_bf16(Arh, Brl, accRR, 0, 0, 0);
    accRR = __builtin_amdgcn_mfma_f32_16x16x32_bf16(Arl, Brh, accRR, 0, 0, 0);
    accII = __builtin_amdgcn_mfma_f32_16x16x32_bf16(Aih, Bih, accII, 0, 0, 0);
    accII = __builtin_amdgcn_mfma_f32_16x16x32_bf16(Aih, Bil, accII, 0, 0, 0);
    accII = __builtin_amdgcn_mfma_f32_16x16x32_bf16(Ail, Bih, accII, 0, 0, 0);
    accRI = __builtin_amdgcn_mfma_f32_16x16x32_bf16(Arh, Bih, accRI, 0, 0, 0);
    accRI = __builtin_amdgcn_mfma_f32_16x16x32_bf16(Arh, Bil, accRI, 0, 0, 0);
    accRI = __builtin_amdgcn_mfma_f32_16x16x32_bf16(Arl, Bih, accRI, 0, 0, 0);
    accIR = __builtin_amdgcn_mfma_f32_16x16x32_bf16(Aih, Brh, accIR, 0, 0, 0);
    accIR = __builtin_amdgcn_mfma_f32_16x16x32_bf16(Aih, Brl, accIR, 0, 0, 0);
    accIR = __builtin_amdgcn_mfma_f32_16x16x32_bf16(Ail, Brh, accIR, 0, 0, 0);
  }

  // epilogue: C/D layout col=l15, row=quad*4+r
  const int cg = cb + nh * 16 + l15;
  const int b = cg / S;
  const int n = cg - b * S;
#pragma unroll
  for (int r = 0; r < 4; ++r) {
    const int m = mb + mh * 16 + quad * 4 + r;
    if (m < S) {
      float Cr = accRR[r] - accII[r];
      float Ci = accRI[r] + accIR[r];
      if (FINAL) {
        float2 pt = PT[n * S + m];
        float tr = Cr * pt.x - Ci * pt.y;
        Ci = Cr * pt.y + Ci * pt.x;
        Cr = tr;
      }
      Sout[(long)(b * S + m) * S + n] = make_float2(Cr, Ci);
    }
  }
}

// ---------------- 10x pixel expansion ----------------
// S4[(b*200+j)*200 + i] = X_b[i][j] (phase applied). out (16,2000,2000,2).
__global__ __launch_bounds__(256) void expand_kernel(
    const float2* __restrict__ S4, float4v* __restrict__ out) {
  unsigned q = blockIdx.x * 256u + threadIdx.x;  // < 32,000,000 exact
  unsigned p0 = q * 2u;
  unsigned b = p0 / 4000000u;
  unsigned rem = p0 - b * 4000000u;
  unsigned r = rem / 2000u;
  unsigned c0 = rem - r * 2000u;
  unsigned i = r / 10u;
  unsigned dr = r - i * 10u;
  float4v o = {0.f, 0.f, 0.f, 0.f};
  if (dr - 1u <= 7u) {  // dr in [1,8]
    unsigned j = c0 / 10u;
    unsigned dc = c0 - j * 10u;  // even: 0,2,4,6,8
    float2 xv = S4[(b * 200u + j) * 200u + i];
    if (dc != 0u) { o.x = xv.x; o.y = xv.y; }
    if (dc != 8u) { o.z = xv.x; o.w = xv.y; }
  }
  __builtin_nontemporal_store(o, &out[q]);  // write-once stream, skip L2 alloc
}

// ---------------- launch ----------------
extern "C" void kernel_launch(void* const* d_in, const int* in_sizes, int n_in,
                              void* d_out, int out_size, void* d_ws, size_t ws_size,
                              hipStream_t stream) {
  const float* waves_real = (const float*)d_in[0];
  const float* waves_imag = (const float*)d_in[1];
  const float* h_real = (const float*)d_in[2];
  const float* h_imag = (const float*)d_in[3];
  const float* voltage = (const float*)d_in[4];
  const float* phase_func = (const float*)d_in[5];
  const float* intensity_func = (const float*)d_in[6];

  float2* HT = (float2*)d_ws;      // 40000
  float2* PT = HT + SS;            // 40000
  float2* S1 = PT + SS;            // 640000 each
  float2* S2 = S1 + SLICE;
  float2* S3 = S2 + SLICE;
  float2* S4 = S3 + SLICE;
  unsigned short* PL = (unsigned short*)(S4 + SLICE);  // 8 * 50176 bf16

  build_planes_ht<<<196, 256, 0, stream>>>(h_real, h_imag, PL, HT);
  gumbel_kernel<<<10000, 256, 0, stream>>>(voltage, phase_func, intensity_func, PT);

  const unsigned short* FP = PL;           // F planes
  const unsigned short* GP = PL + 4 * PS;  // G planes
  dim3 g(7, 100);  // 700 blocks: ~2.7 blocks/CU
  // S1[b*200+m][n] = T1_b[m][n],  T1_b = F @ W_b
  gemm_mfma<0, false><<<g, 256, 0, stream>>>(FP, waves_real, waves_imag,
                                             nullptr, nullptr, nullptr, S1);
  // S2[b*200+m][n] = T2_b[n][m],  T2_b = T1_b @ F  (computed as F @ T1_b^T)
  gemm_mfma<1, false><<<g, 256, 0, stream>>>(FP, nullptr, nullptr, S1,
                                             nullptr, nullptr, S2);
  // S3[b*200+m][n] = T4_b[m][n],  T4_b = G @ (T2_b .* h)
  gemm_mfma<2, false><<<g, 256, 0, stream>>>(GP, nullptr, nullptr, S2,
                                             HT, nullptr, S3);
  // S4[b*200+m][n] = X_b[n][m]*PT, X_b = T4_b @ G  (computed as G @ T4_b^T)
  gemm_mfma<1, true><<<g, 256, 0, stream>>>(GP, nullptr, nullptr, S3,
                                            nullptr, PT, S4);

  expand_kernel<<<125000, 256, 0, stream>>>(S4, (float4v*)d_out);
}